// Round 1
// baseline (99.974 us; speedup 1.0000x reference)
//
#include <hip/hip_runtime.h>

// Problem constants (reference drops the last row: m = N-1 = 768)
#define NP 769
#define M  768
#define REPEL_MARGIN 0.08f
#define MIN_SIZE 0.02f
#define IOU_MARGIN 0.1f

// Intersection area of rectangle i (half-extents wi2,hi2, pose expressed in
// rect j's local frame via offset (tx,ty) and rotation (cc,ss)) with the
// axis-aligned rectangle [-Wj,Wj] x [-Hj,Hj].  Sutherland-Hodgman clip.
__device__ inline float rect_inter_area(float tx, float ty, float cc, float ss,
                                        float wi2, float hi2, float Wj, float Hj) {
    float ax[10], ay[10], bx[10], by[10];
    // corners of rect i in j-local frame
    // dx,dy in {(-w,-h),(w,-h),(w,h),(-w,h)}
    {
        float cw = cc * wi2, sw = ss * wi2, ch = cc * hi2, sh = ss * hi2;
        ax[0] = tx - cw + sh;  ay[0] = ty - sw - ch;   // (-w,-h)
        ax[1] = tx + cw + sh;  ay[1] = ty + sw - ch;   // ( w,-h)
        ax[2] = tx + cw - sh;  ay[2] = ty + sw + ch;   // ( w, h)
        ax[3] = tx - cw - sh;  ay[3] = ty - sw + ch;   // (-w, h)
    }
    int n = 4;
    for (int e = 0; e < 4; ++e) {
        float sgn   = (e & 1) ? -1.0f : 1.0f;
        bool  isY   = (e >= 2);
        float bound = isY ? Hj : Wj;
        int m = 0;
        for (int k = 0; k < n; ++k) {
            int k1 = (k + 1 == n) ? 0 : k + 1;
            float Px = ax[k],  Py = ay[k];
            float Qx = ax[k1], Qy = ay[k1];
            float pv = (isY ? Py : Px) * sgn;
            float qv = (isY ? Qy : Qx) * sgn;
            bool pin = pv <= bound;
            bool qin = qv <= bound;
            if (pin) { bx[m] = Px; by[m] = Py; ++m; }
            if (pin != qin) {
                float t = (bound - pv) / (qv - pv);
                bx[m] = Px + t * (Qx - Px);
                by[m] = Py + t * (Qy - Py);
                ++m;
            }
        }
        n = m;
        for (int k = 0; k < n; ++k) { ax[k] = bx[k]; ay[k] = by[k]; }
        if (n == 0) return 0.0f;
    }
    float area2 = 0.0f;
    for (int k = 0; k < n; ++k) {
        int k1 = (k + 1 == n) ? 0 : k + 1;
        area2 += ax[k] * ay[k1] - ay[k] * ax[k1];
    }
    return 0.5f * fabsf(area2);
}

__global__ void __launch_bounds__(256)
box_repel_loss_kernel(const float* __restrict__ pred, float* __restrict__ out) {
    const int idx = blockIdx.x * blockDim.x + threadIdx.x;
    float contrib = 0.0f;

    if (idx < M * M) {
        const int i = idx / M;
        const int j = idx - i * M;
        const float* bi = pred + 6 * i;
        const float cxi = bi[0], cyi = bi[1], wi = bi[2], hi = bi[3];

        if (i == j) {
            // size penalty for row i (scaled by 1/M), SIZE_WEIGHT = 1
            float sp = fmaxf(MIN_SIZE - wi, 0.0f) + fmaxf(MIN_SIZE - hi, 0.0f);
            contrib = sp * (1.0f / (float)M);
        } else {
            const float* bj = pred + 6 * j;
            const float cxj = bj[0], cyj = bj[1], wj = bj[2], hj = bj[3];
            const float rx = cxi - cxj, ry = cyi - cyj;
            const float d2 = rx * rx + ry * ry;
            const float dist = sqrtf(d2);

            // repel hinge, scaled by 1/(m*(m-1))
            contrib = fmaxf(REPEL_MARGIN - dist, 0.0f) * (1.0f / ((float)M * (float)(M - 1)));

            // bounding-circle early-out for IoU
            const float wi2 = 0.5f * wi, hi2 = 0.5f * hi;
            const float Wj = 0.5f * wj,  Hj = 0.5f * hj;
            const float ri = sqrtf(wi2 * wi2 + hi2 * hi2);
            const float rj = sqrtf(Wj * Wj + Hj * Hj);
            const float rr = ri + rj;
            if (d2 <= rr * rr) {
                const float ci = bi[4], si = bi[5];
                const float cj = bj[4], sj = bj[5];
                // offset of center i in j-local frame
                const float tx =  cj * rx + sj * ry;
                const float ty = -sj * rx + cj * ry;
                // relative rotation R(ai - aj)
                const float cc = ci * cj + si * sj;
                const float ss = si * cj - ci * sj;
                const float inter = rect_inter_area(tx, ty, cc, ss, wi2, hi2, Wj, Hj);
                const float uni = wi * hi + wj * hj - inter;
                const float iou = inter / fmaxf(uni, 1e-12f);
                contrib += fmaxf(iou - IOU_MARGIN, 0.0f) * (1.0f / ((float)M * (float)M));
            }
        }
    }

    // wave (64-lane) shuffle reduction
    float v = contrib;
    #pragma unroll
    for (int off = 32; off > 0; off >>= 1) v += __shfl_down(v, off);

    __shared__ float sdata[4];
    const int lane = threadIdx.x & 63;
    const int wid  = threadIdx.x >> 6;
    if (lane == 0) sdata[wid] = v;
    __syncthreads();
    if (threadIdx.x == 0) {
        float s = sdata[0] + sdata[1] + sdata[2] + sdata[3];
        atomicAdd(out, s);
    }
}

extern "C" void kernel_launch(void* const* d_in, const int* in_sizes, int n_in,
                              void* d_out, int out_size, void* d_ws, size_t ws_size,
                              hipStream_t stream) {
    const float* pred = (const float*)d_in[0];
    float* out = (float*)d_out;

    // d_out is poisoned (0xAA) before every timed launch — zero it on-stream.
    hipMemsetAsync(out, 0, sizeof(float), stream);

    const int total = M * M;
    const int block = 256;
    const int grid = (total + block - 1) / block;
    box_repel_loss_kernel<<<grid, block, 0, stream>>>(pred, out);
}

// Round 2
// 83.705 us; speedup vs baseline: 1.1944x; 1.1944x over previous
//
#include <hip/hip_runtime.h>

#define M  768
#define REPEL_MARGIN 0.08f
#define MIN_SIZE 0.02f
#define IOU_MARGIN 0.1f

// Contribution of one directed source edge to 2*intersection_area.
// (px,py)->(qx,qy): the edge in the CLIPPING rect's local frame (clip to
// |x|<=W, |y|<=H). (bpx,bpy)->(bqx,bqy): the SAME edge in the common
// evaluation frame (B's frame). Liang-Barsky gives frame-invariant t0/t1;
// empty interval collapses to t1==t0 -> cross(S,S)=0. Branchless.
__device__ inline float edge_contrib(float px, float py, float qx, float qy,
                                     float W, float H,
                                     float bpx, float bpy, float bqx, float bqy) {
    float dx = qx - px, dy = qy - py;
    // force away from exact zero (sign irrelevant: both slab t's land on the
    // same +/-huge side, giving "unconstrained" or "empty" correctly)
    dx = (fabsf(dx) < 1e-12f) ? 1e-12f : dx;
    dy = (fabsf(dy) < 1e-12f) ? 1e-12f : dy;
    float rdx = __builtin_amdgcn_rcpf(dx);
    float rdy = __builtin_amdgcn_rcpf(dy);
    float tax = (-W - px) * rdx, tbx = (W - px) * rdx;
    float tay = (-H - py) * rdy, tby = (H - py) * rdy;
    float t0 = fmaxf(fmaxf(fminf(tax, tbx), fminf(tay, tby)), 0.0f);
    float t1 = fminf(fminf(fmaxf(tax, tbx), fmaxf(tay, tby)), 1.0f);
    t1 = fmaxf(t1, t0);                 // empty -> zero-length
    float bdx = bqx - bpx, bdy = bqy - bpy;
    float sx = bpx + t0 * bdx, sy = bpy + t0 * bdy;
    float ex = bpx + t1 * bdx, ey = bpy + t1 * bdy;
    return sx * ey - sy * ex;           // cross(S, E)
}

__global__ void __launch_bounds__(256)
box_repel_loss_kernel(const float* __restrict__ pred, float* __restrict__ out) {
    // 3 blocks per row i -> box i is block-uniform (scalar loads)
    const int i = blockIdx.x / 3;
    const int j = (blockIdx.x - i * 3) * 256 + threadIdx.x;

    const float* bi = pred + 6 * i;
    const float cxi = bi[0], cyi = bi[1], wi = bi[2], hi = bi[3];
    const float ci = bi[4], si = bi[5];

    float contrib;
    if (i == j) {
        // size penalty (SIZE_WEIGHT=1), scaled by 1/M
        contrib = (fmaxf(MIN_SIZE - wi, 0.0f) + fmaxf(MIN_SIZE - hi, 0.0f))
                  * (1.0f / (float)M);
    } else {
        const float* bj = pred + 6 * j;
        const float cxj = bj[0], cyj = bj[1], wj = bj[2], hj = bj[3];
        const float cj = bj[4], sj = bj[5];

        const float rx = cxi - cxj, ry = cyi - cyj;
        const float dist = sqrtf(rx * rx + ry * ry);
        contrib = fmaxf(REPEL_MARGIN - dist, 0.0f)
                  * (1.0f / ((float)M * (float)(M - 1)));

        // ---- rotated IoU, branchless edge-integral form ----
        // Work in j's local frame ("B" frame). A = box i, B = box j.
        const float wa = 0.5f * wi, ha = 0.5f * hi;
        const float wb = 0.5f * wj, hb = 0.5f * hj;
        // A's pose in B frame
        const float tx =  cj * rx + sj * ry;
        const float ty = -sj * rx + cj * ry;
        const float cc = ci * cj + si * sj;     // cos(ai - aj)
        const float ss = si * cj - ci * sj;     // sin(ai - aj)

        // A corners in B frame, CCW
        const float cw = cc * wa, sw = ss * wa, ch = cc * ha, sh = ss * ha;
        const float ax0 = tx - cw + sh, ay0 = ty - sw - ch;
        const float ax1 = tx + cw + sh, ay1 = ty + sw - ch;
        const float ax2 = tx + cw - sh, ay2 = ty + sw + ch;
        const float ax3 = tx - cw - sh, ay3 = ty - sw + ch;

        // B corners in B frame, CCW
        const float bx0 = -wb, by0 = -hb;
        const float bx1 =  wb, by1 = -hb;
        const float bx2 =  wb, by2 =  hb;
        const float bx3 = -wb, by3 =  hb;

        // B corners transformed into A's frame: q = R^T (b - t)
        #define TOA_X(bx, by) ( cc * ((bx) - tx) + ss * ((by) - ty))
        #define TOA_Y(bx, by) (-ss * ((bx) - tx) + cc * ((by) - ty))
        const float qx0 = TOA_X(bx0, by0), qy0 = TOA_Y(bx0, by0);
        const float qx1 = TOA_X(bx1, by1), qy1 = TOA_Y(bx1, by1);
        const float qx2 = TOA_X(bx2, by2), qy2 = TOA_Y(bx2, by2);
        const float qx3 = TOA_X(bx3, by3), qy3 = TOA_Y(bx3, by3);
        #undef TOA_X
        #undef TOA_Y

        float s2 = 0.0f;
        // A's edges: clip in B frame (B axis-aligned), evaluate in B frame
        s2 += edge_contrib(ax0, ay0, ax1, ay1, wb, hb, ax0, ay0, ax1, ay1);
        s2 += edge_contrib(ax1, ay1, ax2, ay2, wb, hb, ax1, ay1, ax2, ay2);
        s2 += edge_contrib(ax2, ay2, ax3, ay3, wb, hb, ax2, ay2, ax3, ay3);
        s2 += edge_contrib(ax3, ay3, ax0, ay0, wb, hb, ax3, ay3, ax0, ay0);
        // B's edges: clip in A frame (A axis-aligned), evaluate in B frame
        s2 += edge_contrib(qx0, qy0, qx1, qy1, wa, ha, bx0, by0, bx1, by1);
        s2 += edge_contrib(qx1, qy1, qx2, qy2, wa, ha, bx1, by1, bx2, by2);
        s2 += edge_contrib(qx2, qy2, qx3, qy3, wa, ha, bx2, by2, bx3, by3);
        s2 += edge_contrib(qx3, qy3, qx0, qy0, wa, ha, bx3, by3, bx0, by0);

        const float inter = fmaxf(0.5f * s2, 0.0f);
        const float uni = wi * hi + wj * hj - inter;
        const float iou = inter / fmaxf(uni, 1e-12f);
        contrib += fmaxf(iou - IOU_MARGIN, 0.0f)
                   * (1.0f / ((float)M * (float)M));
    }

    // wave (64-lane) shuffle reduction
    float v = contrib;
    #pragma unroll
    for (int off = 32; off > 0; off >>= 1) v += __shfl_down(v, off);

    __shared__ float sdata[4];
    const int lane = threadIdx.x & 63;
    const int wid  = threadIdx.x >> 6;
    if (lane == 0) sdata[wid] = v;
    __syncthreads();
    if (threadIdx.x == 0) {
        float s = sdata[0] + sdata[1] + sdata[2] + sdata[3];
        atomicAdd(out, s);
    }
}

extern "C" void kernel_launch(void* const* d_in, const int* in_sizes, int n_in,
                              void* d_out, int out_size, void* d_ws, size_t ws_size,
                              hipStream_t stream) {
    const float* pred = (const float*)d_in[0];
    float* out = (float*)d_out;

    hipMemsetAsync(out, 0, sizeof(float), stream);

    const int grid = M * 3;   // 3 blocks of 256 per row i
    box_repel_loss_kernel<<<grid, 256, 0, stream>>>(pred, out);
}

// Round 3
// 61.416 us; speedup vs baseline: 1.6278x; 1.3629x over previous
//
#include <hip/hip_runtime.h>

#define M  768
#define REPEL_MARGIN 0.08f
#define MIN_SIZE 0.02f
#define IOU_MARGIN 0.1f
#define NBLOCKS (M * 3)   // 3 blocks of 256 per row i -> 2304 partials

// Contribution of one directed source edge to 2*intersection_area.
// (px,py)->(qx,qy): the edge in the CLIPPING rect's local frame (clip to
// |x|<=W, |y|<=H). (bpx,bpy)->(bqx,bqy): the SAME edge in the common
// evaluation frame (B's frame). Liang-Barsky gives frame-invariant t0/t1;
// empty interval collapses to t1==t0 -> cross(S,S)=0. Branchless.
__device__ inline float edge_contrib(float px, float py, float qx, float qy,
                                     float W, float H,
                                     float bpx, float bpy, float bqx, float bqy) {
    float dx = qx - px, dy = qy - py;
    dx = (fabsf(dx) < 1e-12f) ? 1e-12f : dx;
    dy = (fabsf(dy) < 1e-12f) ? 1e-12f : dy;
    float rdx = __builtin_amdgcn_rcpf(dx);
    float rdy = __builtin_amdgcn_rcpf(dy);
    float tax = (-W - px) * rdx, tbx = (W - px) * rdx;
    float tay = (-H - py) * rdy, tby = (H - py) * rdy;
    float t0 = fmaxf(fmaxf(fminf(tax, tbx), fminf(tay, tby)), 0.0f);
    float t1 = fminf(fminf(fmaxf(tax, tbx), fmaxf(tay, tby)), 1.0f);
    t1 = fmaxf(t1, t0);                 // empty -> zero-length
    float bdx = bqx - bpx, bdy = bqy - bpy;
    float sx = bpx + t0 * bdx, sy = bpy + t0 * bdy;
    float ex = bpx + t1 * bdx, ey = bpy + t1 * bdy;
    return sx * ey - sy * ex;           // cross(S, E)
}

__global__ void __launch_bounds__(256)
box_repel_stage1(const float* __restrict__ pred, float* __restrict__ partial) {
    // 3 blocks per row i -> box i is block-uniform (scalar loads)
    const int i = blockIdx.x / 3;
    const int j = (blockIdx.x - i * 3) * 256 + threadIdx.x;

    const float* bi = pred + 6 * i;
    const float cxi = bi[0], cyi = bi[1], wi = bi[2], hi = bi[3];
    const float ci = bi[4], si = bi[5];

    float contrib;
    if (i == j) {
        contrib = (fmaxf(MIN_SIZE - wi, 0.0f) + fmaxf(MIN_SIZE - hi, 0.0f))
                  * (1.0f / (float)M);
    } else {
        const float* bj = pred + 6 * j;
        const float cxj = bj[0], cyj = bj[1], wj = bj[2], hj = bj[3];
        const float cj = bj[4], sj = bj[5];

        const float rx = cxi - cxj, ry = cyi - cyj;
        const float dist = sqrtf(rx * rx + ry * ry);
        contrib = fmaxf(REPEL_MARGIN - dist, 0.0f)
                  * (1.0f / ((float)M * (float)(M - 1)));

        // ---- rotated IoU, branchless edge-integral form ----
        const float wa = 0.5f * wi, ha = 0.5f * hi;
        const float wb = 0.5f * wj, hb = 0.5f * hj;
        const float tx =  cj * rx + sj * ry;
        const float ty = -sj * rx + cj * ry;
        const float cc = ci * cj + si * sj;     // cos(ai - aj)
        const float ss = si * cj - ci * sj;     // sin(ai - aj)

        // A corners in B frame, CCW
        const float cw = cc * wa, sw = ss * wa, ch = cc * ha, sh = ss * ha;
        const float ax0 = tx - cw + sh, ay0 = ty - sw - ch;
        const float ax1 = tx + cw + sh, ay1 = ty + sw - ch;
        const float ax2 = tx + cw - sh, ay2 = ty + sw + ch;
        const float ax3 = tx - cw - sh, ay3 = ty - sw + ch;

        // B corners in B frame, CCW
        const float bx0 = -wb, by0 = -hb;
        const float bx1 =  wb, by1 = -hb;
        const float bx2 =  wb, by2 =  hb;
        const float bx3 = -wb, by3 =  hb;

        // B corners in A's frame: q = R^T (b - t)
        #define TOA_X(bx, by) ( cc * ((bx) - tx) + ss * ((by) - ty))
        #define TOA_Y(bx, by) (-ss * ((bx) - tx) + cc * ((by) - ty))
        const float qx0 = TOA_X(bx0, by0), qy0 = TOA_Y(bx0, by0);
        const float qx1 = TOA_X(bx1, by1), qy1 = TOA_Y(bx1, by1);
        const float qx2 = TOA_X(bx2, by2), qy2 = TOA_Y(bx2, by2);
        const float qx3 = TOA_X(bx3, by3), qy3 = TOA_Y(bx3, by3);
        #undef TOA_X
        #undef TOA_Y

        float s2 = 0.0f;
        // A's edges: clip in B frame, evaluate in B frame
        s2 += edge_contrib(ax0, ay0, ax1, ay1, wb, hb, ax0, ay0, ax1, ay1);
        s2 += edge_contrib(ax1, ay1, ax2, ay2, wb, hb, ax1, ay1, ax2, ay2);
        s2 += edge_contrib(ax2, ay2, ax3, ay3, wb, hb, ax2, ay2, ax3, ay3);
        s2 += edge_contrib(ax3, ay3, ax0, ay0, wb, hb, ax3, ay3, ax0, ay0);
        // B's edges: clip in A frame, evaluate in B frame
        s2 += edge_contrib(qx0, qy0, qx1, qy1, wa, ha, bx0, by0, bx1, by1);
        s2 += edge_contrib(qx1, qy1, qx2, qy2, wa, ha, bx1, by1, bx2, by2);
        s2 += edge_contrib(qx2, qy2, qx3, qy3, wa, ha, bx2, by2, bx3, by3);
        s2 += edge_contrib(qx3, qy3, qx0, qy0, wa, ha, bx3, by3, bx0, by0);

        const float inter = fmaxf(0.5f * s2, 0.0f);
        const float uni = wi * hi + wj * hj - inter;
        const float iou = inter / fmaxf(uni, 1e-12f);
        contrib += fmaxf(iou - IOU_MARGIN, 0.0f)
                   * (1.0f / ((float)M * (float)M));
    }

    // wave (64-lane) shuffle reduction
    float v = contrib;
    #pragma unroll
    for (int off = 32; off > 0; off >>= 1) v += __shfl_down(v, off);

    __shared__ float sdata[4];
    const int lane = threadIdx.x & 63;
    const int wid  = threadIdx.x >> 6;
    if (lane == 0) sdata[wid] = v;
    __syncthreads();
    if (threadIdx.x == 0) {
        // plain store — no atomics, no contention
        partial[blockIdx.x] = sdata[0] + sdata[1] + sdata[2] + sdata[3];
    }
}

__global__ void __launch_bounds__(256)
box_repel_stage2(const float* __restrict__ partial, float* __restrict__ out) {
    float v = 0.0f;
    // NBLOCKS = 2304 = 9 * 256
    #pragma unroll
    for (int k = 0; k < NBLOCKS / 256; ++k)
        v += partial[k * 256 + threadIdx.x];

    #pragma unroll
    for (int off = 32; off > 0; off >>= 1) v += __shfl_down(v, off);

    __shared__ float sdata[4];
    const int lane = threadIdx.x & 63;
    const int wid  = threadIdx.x >> 6;
    if (lane == 0) sdata[wid] = v;
    __syncthreads();
    if (threadIdx.x == 0)
        out[0] = sdata[0] + sdata[1] + sdata[2] + sdata[3];   // direct store, no memset needed
}

extern "C" void kernel_launch(void* const* d_in, const int* in_sizes, int n_in,
                              void* d_out, int out_size, void* d_ws, size_t ws_size,
                              hipStream_t stream) {
    const float* pred = (const float*)d_in[0];
    float* out = (float*)d_out;
    float* partial = (float*)d_ws;     // 2304 * 4 B = 9 KB of the workspace

    box_repel_stage1<<<NBLOCKS, 256, 0, stream>>>(pred, partial);
    box_repel_stage2<<<1, 256, 0, stream>>>(partial, out);
}

// Round 4
// 58.302 us; speedup vs baseline: 1.7148x; 1.0534x over previous
//
#include <hip/hip_runtime.h>

#define M  768
#define HALF (M / 2)      // 384
#define REPEL_MARGIN 0.08f
#define MIN_SIZE 0.02f
#define IOU_MARGIN 0.1f
#define NBLOCKS M         // one block per row r, 384 threads = M/2 pairs

// Contribution of one directed source edge to 2*intersection_area.
// (px,py)->(qx,qy): the edge in the CLIPPING rect's local frame (clip to
// |x|<=W, |y|<=H). (bpx,bpy)->(bqx,bqy): the SAME edge in the common
// evaluation frame (B's frame). Liang-Barsky gives frame-invariant t0/t1;
// empty interval collapses to t1==t0 -> cross(S,S)=0. Branchless.
__device__ inline float edge_contrib(float px, float py, float qx, float qy,
                                     float W, float H,
                                     float bpx, float bpy, float bqx, float bqy) {
    float dx = qx - px, dy = qy - py;
    dx = (fabsf(dx) < 1e-12f) ? 1e-12f : dx;
    dy = (fabsf(dy) < 1e-12f) ? 1e-12f : dy;
    float rdx = __builtin_amdgcn_rcpf(dx);
    float rdy = __builtin_amdgcn_rcpf(dy);
    float tax = (-W - px) * rdx, tbx = (W - px) * rdx;
    float tay = (-H - py) * rdy, tby = (H - py) * rdy;
    float t0 = fmaxf(fmaxf(fminf(tax, tbx), fminf(tay, tby)), 0.0f);
    float t1 = fminf(fminf(fmaxf(tax, tbx), fmaxf(tay, tby)), 1.0f);
    t1 = fmaxf(t1, t0);                 // empty -> zero-length
    float bdx = bqx - bpx, bdy = bqy - bpy;
    float sx = bpx + t0 * bdx, sy = bpy + t0 * bdy;
    float ex = bpx + t1 * bdx, ey = bpy + t1 * bdy;
    return sx * ey - sy * ex;           // cross(S, E)
}

// Round-robin triangle enumeration: block r, thread t -> pair (r, (r+1+t) mod M).
// Circular distance d = t+1 in [1, M/2]. d < M/2: pair appears once -> weight 2.
// d == M/2: pair appears twice (from both endpoints) -> weight 1 each.
__global__ void __launch_bounds__(384)
box_repel_stage1(const float* __restrict__ pred, float* __restrict__ partial) {
    const int r = blockIdx.x;
    const int d = threadIdx.x + 1;            // 1 .. 384
    int j = r + d; if (j >= M) j -= M;

    const float* bi = pred + 6 * r;           // block-uniform -> scalar loads
    const float cxi = bi[0], cyi = bi[1], wi = bi[2], hi = bi[3];
    const float ci = bi[4], si = bi[5];

    const float* bj = pred + 6 * j;
    const float cxj = bj[0], cyj = bj[1], wj = bj[2], hj = bj[3];
    const float cj = bj[4], sj = bj[5];

    const float rx = cxi - cxj, ry = cyi - cyj;
    const float dist = sqrtf(rx * rx + ry * ry);
    float contrib = fmaxf(REPEL_MARGIN - dist, 0.0f)
                    * (1.0f / ((float)M * (float)(M - 1)));

    // ---- rotated IoU, branchless edge-integral form ----
    const float wa = 0.5f * wi, ha = 0.5f * hi;
    const float wb = 0.5f * wj, hb = 0.5f * hj;
    const float tx =  cj * rx + sj * ry;
    const float ty = -sj * rx + cj * ry;
    const float cc = ci * cj + si * sj;       // cos(ai - aj)
    const float ss = si * cj - ci * sj;       // sin(ai - aj)

    // A corners in B frame, CCW
    const float cw = cc * wa, sw = ss * wa, ch = cc * ha, sh = ss * ha;
    const float ax0 = tx - cw + sh, ay0 = ty - sw - ch;
    const float ax1 = tx + cw + sh, ay1 = ty + sw - ch;
    const float ax2 = tx + cw - sh, ay2 = ty + sw + ch;
    const float ax3 = tx - cw - sh, ay3 = ty - sw + ch;

    // B corners in B frame, CCW
    const float bx0 = -wb, by0 = -hb;
    const float bx1 =  wb, by1 = -hb;
    const float bx2 =  wb, by2 =  hb;
    const float bx3 = -wb, by3 =  hb;

    // B corners in A's frame: q = R^T (b - t)
    #define TOA_X(bx, by) ( cc * ((bx) - tx) + ss * ((by) - ty))
    #define TOA_Y(bx, by) (-ss * ((bx) - tx) + cc * ((by) - ty))
    const float qx0 = TOA_X(bx0, by0), qy0 = TOA_Y(bx0, by0);
    const float qx1 = TOA_X(bx1, by1), qy1 = TOA_Y(bx1, by1);
    const float qx2 = TOA_X(bx2, by2), qy2 = TOA_Y(bx2, by2);
    const float qx3 = TOA_X(bx3, by3), qy3 = TOA_Y(bx3, by3);
    #undef TOA_X
    #undef TOA_Y

    float s2 = 0.0f;
    // A's edges: clip in B frame, evaluate in B frame
    s2 += edge_contrib(ax0, ay0, ax1, ay1, wb, hb, ax0, ay0, ax1, ay1);
    s2 += edge_contrib(ax1, ay1, ax2, ay2, wb, hb, ax1, ay1, ax2, ay2);
    s2 += edge_contrib(ax2, ay2, ax3, ay3, wb, hb, ax2, ay2, ax3, ay3);
    s2 += edge_contrib(ax3, ay3, ax0, ay0, wb, hb, ax3, ay3, ax0, ay0);
    // B's edges: clip in A frame, evaluate in B frame
    s2 += edge_contrib(qx0, qy0, qx1, qy1, wa, ha, bx0, by0, bx1, by1);
    s2 += edge_contrib(qx1, qy1, qx2, qy2, wa, ha, bx1, by1, bx2, by2);
    s2 += edge_contrib(qx2, qy2, qx3, qy3, wa, ha, bx2, by2, bx3, by3);
    s2 += edge_contrib(qx3, qy3, qx0, qy0, wa, ha, bx3, by3, bx0, by0);

    const float inter = fmaxf(0.5f * s2, 0.0f);
    const float uni = wi * hi + wj * hj - inter;
    const float iou = inter / fmaxf(uni, 1e-12f);
    contrib += fmaxf(iou - IOU_MARGIN, 0.0f)
               * (1.0f / ((float)M * (float)M));

    // symmetry weight: each unordered pair counted twice in the reference
    const float w = (d == HALF) ? 1.0f : 2.0f;
    contrib *= w;

    // diagonal (size penalty) for row r, once per block
    if (threadIdx.x == 0) {
        contrib += (fmaxf(MIN_SIZE - wi, 0.0f) + fmaxf(MIN_SIZE - hi, 0.0f))
                   * (1.0f / (float)M);
    }

    // wave (64-lane) shuffle reduction, 6 waves per block
    float v = contrib;
    #pragma unroll
    for (int off = 32; off > 0; off >>= 1) v += __shfl_down(v, off);

    __shared__ float sdata[6];
    const int lane = threadIdx.x & 63;
    const int wid  = threadIdx.x >> 6;
    if (lane == 0) sdata[wid] = v;
    __syncthreads();
    if (threadIdx.x == 0) {
        float s = sdata[0] + sdata[1] + sdata[2]
                + sdata[3] + sdata[4] + sdata[5];
        partial[blockIdx.x] = s;          // plain store, no atomics
    }
}

__global__ void __launch_bounds__(256)
box_repel_stage2(const float* __restrict__ partial, float* __restrict__ out) {
    float v = 0.0f;
    // NBLOCKS = 768 = 3 * 256
    #pragma unroll
    for (int k = 0; k < NBLOCKS / 256; ++k)
        v += partial[k * 256 + threadIdx.x];

    #pragma unroll
    for (int off = 32; off > 0; off >>= 1) v += __shfl_down(v, off);

    __shared__ float sdata[4];
    const int lane = threadIdx.x & 63;
    const int wid  = threadIdx.x >> 6;
    if (lane == 0) sdata[wid] = v;
    __syncthreads();
    if (threadIdx.x == 0)
        out[0] = sdata[0] + sdata[1] + sdata[2] + sdata[3];
}

extern "C" void kernel_launch(void* const* d_in, const int* in_sizes, int n_in,
                              void* d_out, int out_size, void* d_ws, size_t ws_size,
                              hipStream_t stream) {
    const float* pred = (const float*)d_in[0];
    float* out = (float*)d_out;
    float* partial = (float*)d_ws;     // 768 * 4 B of workspace

    box_repel_stage1<<<NBLOCKS, 384, 0, stream>>>(pred, partial);
    box_repel_stage2<<<1, 256, 0, stream>>>(partial, out);
}